// Round 1
// baseline (252.414 us; speedup 1.0000x reference)
//
#include <hip/hip_runtime.h>

typedef unsigned short u16;
typedef __bf16 bf16x8 __attribute__((ext_vector_type(8)));
typedef float f32x4 __attribute__((ext_vector_type(4)));

#define LOG2E 1.44269504088896f

__device__ inline u16 f2b(float f) {
    unsigned u = __float_as_uint(f);
    u += 0x7fff + ((u >> 16) & 1);
    return (u16)(u >> 16);
}
__device__ inline float b2f(u16 u) { return __uint_as_float(((unsigned)u) << 16); }
__device__ inline unsigned pk2(float a, float b) {
    return (unsigned)f2b(a) | ((unsigned)f2b(b) << 16);
}
__device__ inline uint4 pack8(float4 a, float4 b) {
    return uint4{pk2(a.x, a.y), pk2(a.z, a.w), pk2(b.x, b.y), pk2(b.z, b.w)};
}
__device__ inline f32x4 mfma_bf16(uint4 a, uint4 b, f32x4 c) {
    return __builtin_amdgcn_mfma_f32_16x16x32_bf16(
        __builtin_bit_cast(bf16x8, a), __builtin_bit_cast(bf16x8, b), c, 0, 0, 0);
}
// async global->LDS, 16 B per lane; LDS dest = wave-uniform base + lane*16
__device__ inline void ld16(const u16* g, u16* l) {
    __builtin_amdgcn_global_load_lds(
        (const __attribute__((address_space(1))) unsigned int*)g,
        (__attribute__((address_space(3))) unsigned int*)l, 16, 0, 0);
}

// LDS swizzle scheme (all MFMA tiles, [row][32] u16, 64 B rows):
//   logical 16B granule (row, q) lives at byte  row*64 + (q ^ ((row>>1)&3))*16.
// Read side:  qs = (q ^ ((l15>>1)&3))*8   (u16 units; valid because every read
//   row is  base + l15 with base ≡ 0 mod 8, so (row>>1)&3 == (l15>>1)&3).
// Stage side (global_load_lds writes LINEARLY, rule #21): lane L's dest granule
//   is (row = sweepbase + (L>>2), pq = L&3); pre-swizzle the GLOBAL source:
//   sq = ((L&3) ^ ((L>>3)&3))*8  (uniform across sweeps/waves: offsets ≡ 0 mod 4
//   after >>1&3).  16 lanes of a fragment read then cover 8 distinct 16B slots
//   (2-way = free) and the full wave covers each 1 KB stripe exactly once.

// ---------------------------------------------------------------------------
// Weight prep (f32 -> bf16):
//   WkT[e][d] = Wqk[1][d][e],  WvT[e][d] = Wv[d][e],  Wqb[c][d] = Wqk[0][c][d]
// ---------------------------------------------------------------------------
__global__ __launch_bounds__(256) void prep_w(const float* __restrict__ Wqk,
                                              const float* __restrict__ Wv,
                                              u16* __restrict__ WkT,
                                              u16* __restrict__ WvT,
                                              u16* __restrict__ Wqb) {
    int idx = blockIdx.x * 256 + threadIdx.x;   // 0 .. 196607
    int which = idx >> 16;
    int i = (idx >> 8) & 255;
    int j = idx & 255;
    if (which == 0)
        WkT[i * 256 + j] = f2b(Wqk[65536 + j * 256 + i]);
    else if (which == 1)
        WvT[i * 256 + j] = f2b(Wv[j * 256 + i]);
    else
        Wqb[i * 256 + j] = f2b(Wqk[i * 256 + j]);
}

// ---------------------------------------------------------------------------
// Fused K+V projection, FULL-WIDTH (64 rows x 256 cols x {K,V}) per block.
// v2: 2-phase single-barrier pipeline (stage k+1 while MFMAing k), XOR-swizzled
// LDS (conflict-free ds_read_b128), column-split wave tiling (4x4 frags/wave:
// 12 LDS reads + 32 MFMA per k-step instead of 33 reads), depth-2 A prefetch.
// LDS: As[2][2048] @0 | B[2][ K 8192 | V 8192 ] @4096 = 36864 u16 = 72 KB.
// ---------------------------------------------------------------------------
__global__ __launch_bounds__(256, 2) void gemm_kv(const float* __restrict__ A,
                                                  const u16* __restrict__ BtK,
                                                  const u16* __restrict__ BtV,
                                                  const float* __restrict__ biasK,
                                                  const float* __restrict__ biasV,
                                                  u16* __restrict__ KT,
                                                  u16* __restrict__ VT) {
    __shared__ __align__(16) u16 lds[36864];

    const int t = threadIdx.x;
    const int r0 = blockIdx.x * 64;
    const int w = t >> 6, lane = t & 63, l15 = lane & 15, q = lane >> 4;
    const int sq = ((lane & 3) ^ ((lane >> 3) & 3)) * 8;  // staging src swizzle
    const int qs = (q ^ ((l15 >> 1) & 3)) * 8;            // frag read swizzle
    const int awoff = (t >> 2) * 32 + sq;                 // swizzled A ds_write
    const int brr = t >> 2;

    f32x4 accK[4][4], accV[4][4];
#pragma unroll
    for (int rt = 0; rt < 4; ++rt)
#pragma unroll
        for (int ct = 0; ct < 4; ++ct) {
            accK[rt][ct] = f32x4{0.f, 0.f, 0.f, 0.f};
            accV[rt][ct] = f32x4{0.f, 0.f, 0.f, 0.f};
        }

    const float* Arow = A + (long)(r0 + brr) * 256 + (t & 3) * 8;
    // depth-2 rotating A prefetch: slice k8 = 8 floats at Arow + k8*32
    float4 p0 = ((const float4*)Arow)[0], p1 = ((const float4*)Arow)[1];
    float4 c0_ = *(const float4*)(Arow + 32), c1_ = *(const float4*)(Arow + 36);
    float4 d0_ = *(const float4*)(Arow + 64), d1_ = *(const float4*)(Arow + 68);

    // prologue: stage k0=0 into buffer 0
    {
        u16* dK = lds + 4096 + w * 512;
#pragma unroll
        for (int j = 0; j < 4; ++j) {
            int br = j * 64 + brr;
            ld16(BtK + br * 256 + sq, dK + j * 2048);
            ld16(BtV + br * 256 + sq, dK + 8192 + j * 2048);
        }
    }
    *(uint4*)(lds + awoff) = pack8(p0, p1);
    __syncthreads();

#pragma unroll
    for (int t8 = 0; t8 < 8; ++t8) {
        const int cur = t8 & 1;
        if (t8 < 7) {  // stage next k-slab into the other buffer (async)
            const int k0 = (t8 + 1) * 32;
            u16* dK = lds + 4096 + (cur ^ 1) * 16384 + w * 512;
#pragma unroll
            for (int j = 0; j < 4; ++j) {
                int br = j * 64 + brr;
                ld16(BtK + br * 256 + k0 + sq, dK + j * 2048);
                ld16(BtV + br * 256 + k0 + sq, dK + 8192 + j * 2048);
            }
            *(uint4*)(lds + (cur ^ 1) * 2048 + awoff) = pack8(c0_, c1_);
            c0_ = d0_; c1_ = d1_;
            if (t8 < 5) {
                d0_ = *(const float4*)(Arow + (t8 + 3) * 32);
                d1_ = *(const float4*)(Arow + (t8 + 3) * 32 + 4);
            }
        }
        const u16* Asc = lds + cur * 2048;
        const u16* Bc = lds + 4096 + cur * 16384;
        uint4 af[4];
#pragma unroll
        for (int rt = 0; rt < 4; ++rt)
            af[rt] = *(const uint4*)(Asc + (rt * 16 + l15) * 32 + qs);
#pragma unroll
        for (int ct = 0; ct < 4; ++ct) {
            const int bo = (w * 64 + ct * 16 + l15) * 32 + qs;
            uint4 bK = *(const uint4*)(Bc + bo);
            uint4 bV = *(const uint4*)(Bc + 8192 + bo);
#pragma unroll
            for (int rt = 0; rt < 4; ++rt) {
                accK[rt][ct] = mfma_bf16(af[rt], bK, accK[rt][ct]);
                accV[rt][ct] = mfma_bf16(af[rt], bV, accV[rt][ct]);
            }
        }
        __syncthreads();  // drains this iter's stage (covered by MFMA phase)
    }

    // epilogue: bias + transpose through LDS (256 x 72 u16 = 36 KB), K then V
    const int bb = r0 >> 13, n0 = r0 & 8191;
    u16* Ct = lds;
#pragma unroll
    for (int pass = 0; pass < 2; ++pass) {
        const f32x4(*acc)[4] = pass ? accV : accK;
        const float* bias = pass ? biasV : biasK;
        u16* CT = pass ? VT : KT;
#pragma unroll
        for (int ct = 0; ct < 4; ++ct) {
            const int col = w * 64 + ct * 16 + l15;
            const float bv = bias[col];
#pragma unroll
            for (int rt = 0; rt < 4; ++rt) {
                ushort4 pk;
                pk.x = f2b(acc[rt][ct][0] + bv);
                pk.y = f2b(acc[rt][ct][1] + bv);
                pk.z = f2b(acc[rt][ct][2] + bv);
                pk.w = f2b(acc[rt][ct][3] + bv);
                *(ushort4*)&Ct[col * 72 + rt * 16 + q * 4] = pk;
            }
        }
        __syncthreads();
        long off = ((long)bb * 256 + t) * 8192 + n0;
#pragma unroll
        for (int j = 0; j < 8; ++j)
            *(uint4*)(CT + off + j * 8) = *(const uint4*)&Ct[t * 72 + j * 8];
        __syncthreads();
    }
}

// ---------------------------------------------------------------------------
// Output GEMM, FULL-WIDTH: out[b][n][e] = sum_c X[b][n][c]*WfoldT[(b,e)][c]
// + outb[b][e].  Same v2 structure as gemm_kv (single B matrix).
// LDS: As[2][2048] @0 | Bs[2][8192] @4096 = 20480 u16 = 40 KB.
// ---------------------------------------------------------------------------
__global__ __launch_bounds__(256, 3) void gemm_out(const float* __restrict__ A,
                                                   const u16* __restrict__ WfoldT,
                                                   const float* __restrict__ outb,
                                                   float* __restrict__ C) {
    __shared__ __align__(16) u16 lds[20480];
    const int t = threadIdx.x;
    const int r0 = blockIdx.x * 64;
    const int bb = r0 >> 13;
    const int w = t >> 6, lane = t & 63, l15 = lane & 15, q = lane >> 4;
    const int sq = ((lane & 3) ^ ((lane >> 3) & 3)) * 8;
    const int qs = (q ^ ((l15 >> 1) & 3)) * 8;
    const int awoff = (t >> 2) * 32 + sq;
    const int brr = t >> 2;
    const u16* Bt = WfoldT + (long)bb * 65536;

    f32x4 acc[4][4];
#pragma unroll
    for (int rt = 0; rt < 4; ++rt)
#pragma unroll
        for (int ct = 0; ct < 4; ++ct) acc[rt][ct] = f32x4{0.f, 0.f, 0.f, 0.f};

    const float* Arow = A + (long)(r0 + brr) * 256 + (t & 3) * 8;
    float4 p0 = ((const float4*)Arow)[0], p1 = ((const float4*)Arow)[1];
    float4 c0_ = *(const float4*)(Arow + 32), c1_ = *(const float4*)(Arow + 36);
    float4 d0_ = *(const float4*)(Arow + 64), d1_ = *(const float4*)(Arow + 68);

    {
        u16* dB = lds + 4096 + w * 512;
#pragma unroll
        for (int j = 0; j < 4; ++j)
            ld16(Bt + (j * 64 + brr) * 256 + sq, dB + j * 2048);
    }
    *(uint4*)(lds + awoff) = pack8(p0, p1);
    __syncthreads();

#pragma unroll
    for (int t8 = 0; t8 < 8; ++t8) {
        const int cur = t8 & 1;
        if (t8 < 7) {
            const int k0 = (t8 + 1) * 32;
            u16* dB = lds + 4096 + (cur ^ 1) * 8192 + w * 512;
#pragma unroll
            for (int j = 0; j < 4; ++j)
                ld16(Bt + (j * 64 + brr) * 256 + k0 + sq, dB + j * 2048);
            *(uint4*)(lds + (cur ^ 1) * 2048 + awoff) = pack8(c0_, c1_);
            c0_ = d0_; c1_ = d1_;
            if (t8 < 5) {
                d0_ = *(const float4*)(Arow + (t8 + 3) * 32);
                d1_ = *(const float4*)(Arow + (t8 + 3) * 32 + 4);
            }
        }
        const u16* Asc = lds + cur * 2048;
        const u16* Bc = lds + 4096 + cur * 8192;
        uint4 af[4];
#pragma unroll
        for (int rt = 0; rt < 4; ++rt)
            af[rt] = *(const uint4*)(Asc + (rt * 16 + l15) * 32 + qs);
#pragma unroll
        for (int ct = 0; ct < 4; ++ct) {
            uint4 bf = *(const uint4*)(Bc + (w * 64 + ct * 16 + l15) * 32 + qs);
#pragma unroll
            for (int rt = 0; rt < 4; ++rt)
                acc[rt][ct] = mfma_bf16(af[rt], bf, acc[rt][ct]);
        }
        __syncthreads();
    }

#pragma unroll
    for (int ct = 0; ct < 4; ++ct) {
        const int col = w * 64 + ct * 16 + l15;
        const float bv = outb[bb * 256 + col];
#pragma unroll
        for (int rt = 0; rt < 4; ++rt) {
#pragma unroll
            for (int r = 0; r < 4; ++r) {
                int row = r0 + rt * 16 + q * 4 + r;
                C[(long)row * 256 + col] = acc[rt][ct][r] + bv;
            }
        }
    }
}

// ---------------------------------------------------------------------------
// Split-K lam GEMM, 128x128 tiles: lamP[s][(b,e)][d] over chunk s of n.
// v2 structure: 2-phase dbuf + swizzle + column-split tiling (8x2 frags/wave,
// 10 LDS reads + 16 MFMA per k-step instead of 24 reads).
// LDS: buf[2] x (As 4096 | Bs 4096) = 16384 u16 = 32 KB.
// ---------------------------------------------------------------------------
__global__ __launch_bounds__(256, 2) void gemm_splitk(const u16* __restrict__ VT,
                                                      const u16* __restrict__ PT,
                                                      float* __restrict__ lamP,
                                                      int chunk) {
    __shared__ __align__(16) u16 lds[16384];
    const int t = threadIdx.x;
    const int r0 = blockIdx.x * 128;   // (b,e) rows
    const int c0 = blockIdx.y * 128;   // d cols
    const int s = blockIdx.z;
    const int bb = blockIdx.x >> 1;
    const long n0 = (long)s * chunk;
    const int w = t >> 6, lane = t & 63, l15 = lane & 15, q = lane >> 4;
    const int sq = ((lane & 3) ^ ((lane >> 3) & 3)) * 8;
    const int qs = (q ^ ((l15 >> 1) & 3)) * 8;
    const int brr = t >> 2;

    const u16* Abase = VT + (long)r0 * 8192 + n0;
    const u16* Bbase = PT + ((long)bb * 256 + c0) * 8192 + n0;

    f32x4 acc[8][2];
#pragma unroll
    for (int rt = 0; rt < 8; ++rt) {
        acc[rt][0] = f32x4{0.f, 0.f, 0.f, 0.f};
        acc[rt][1] = f32x4{0.f, 0.f, 0.f, 0.f};
    }

    {
        u16* dA = lds + w * 512;
#pragma unroll
        for (int j = 0; j < 2; ++j) {
            int br = j * 64 + brr;
            ld16(Abase + (long)br * 8192 + sq, dA + j * 2048);
            ld16(Bbase + (long)br * 8192 + sq, dA + 4096 + j * 2048);
        }
    }
    __syncthreads();

    const int nk = chunk >> 5;
    for (int ks = 0; ks < nk; ++ks) {
        const int cur = ks & 1;
        if (ks + 1 < nk) {
            const int k0 = (ks + 1) * 32;
            u16* dA = lds + (cur ^ 1) * 8192 + w * 512;
#pragma unroll
            for (int j = 0; j < 2; ++j) {
                int br = j * 64 + brr;
                ld16(Abase + (long)br * 8192 + k0 + sq, dA + j * 2048);
                ld16(Bbase + (long)br * 8192 + k0 + sq, dA + 4096 + j * 2048);
            }
        }
        const u16* Asc = lds + cur * 8192;
        const u16* Bsc = Asc + 4096;
        const int bo = (w * 32 + l15) * 32 + qs;
        uint4 bf0 = *(const uint4*)(Bsc + bo);
        uint4 bf1 = *(const uint4*)(Bsc + 512 + bo);  // +16 rows
#pragma unroll
        for (int rt = 0; rt < 8; ++rt) {
            uint4 af = *(const uint4*)(Asc + (rt * 16 + l15) * 32 + qs);
            acc[rt][0] = mfma_bf16(af, bf0, acc[rt][0]);
            acc[rt][1] = mfma_bf16(af, bf1, acc[rt][1]);
        }
        __syncthreads();
    }

    float* outp = lamP + (long)s * 524288;
#pragma unroll
    for (int rt = 0; rt < 8; ++rt)
#pragma unroll
        for (int ct = 0; ct < 2; ++ct) {
            const int col = c0 + w * 32 + ct * 16 + l15;
#pragma unroll
            for (int r = 0; r < 4; ++r)
                outp[(long)(r0 + rt * 16 + q * 4 + r) * 256 + col] = acc[rt][ct][r];
        }
}

// ---------------------------------------------------------------------------
// lamT[i] = sum_s lamP[s][i]   (coalesced float4)
// ---------------------------------------------------------------------------
__global__ __launch_bounds__(256) void reduce_lam(const float* __restrict__ lamP,
                                                  float* __restrict__ lamT, int S) {
    int i = blockIdx.x * 256 + threadIdx.x;  // float4 index, 131072 total
    float4 v = ((const float4*)lamP)[i];
    for (int s = 1; s < S; ++s) {
        float4 p = ((const float4*)(lamP + (long)s * 524288))[i];
        v.x += p.x; v.y += p.y; v.z += p.z; v.w += p.w;
    }
    ((float4*)lamT)[i] = v;
}

// ---------------------------------------------------------------------------
// Fold GEMM: WfoldT[(b,e)][c] = sum_d bnT[(b,e)][d] * Wqb[c][d].
// 2048 rows x 256 cols, K=256.  Tile 64x64, grid (32,4).
// ---------------------------------------------------------------------------
__global__ __launch_bounds__(256, 4) void gemm_fold(const u16* __restrict__ Abn,
                                                    const u16* __restrict__ Wqb,
                                                    u16* __restrict__ WfoldT) {
    __shared__ __align__(16) u16 lds[4096];  // As 64x32, Bs 64x32
    u16* As = lds;
    u16* Bs = lds + 2048;

    const int t = threadIdx.x;
    const int r0 = blockIdx.x * 64;
    const int c0 = blockIdx.y * 64;
    const int w = t >> 6, lane = t & 63, l15 = lane & 15, q = lane >> 4;

    f32x4 acc[4];
#pragma unroll
    for (int c = 0; c < 4; ++c) acc[c] = f32x4{0.f, 0.f, 0.f, 0.f};

    const int br = t >> 2;
    const int bk = (t & 3) * 8;

    for (int k0 = 0; k0 < 256; k0 += 32) {
        ld16(Abn + (long)(r0 + br) * 256 + k0 + bk, As + w * 512);
        ld16(Wqb + (long)(c0 + br) * 256 + k0 + bk, Bs + w * 512);
        __syncthreads();
        uint4 af = *(const uint4*)(As + (w * 16 + l15) * 32 + q * 8);
#pragma unroll
        for (int c = 0; c < 4; ++c) {
            uint4 bf = *(const uint4*)(Bs + (c * 16 + l15) * 32 + q * 8);
            acc[c] = mfma_bf16(af, bf, acc[c]);
        }
        __syncthreads();
    }

#pragma unroll
    for (int c = 0; c < 4; ++c) {
        int col = c0 + c * 16 + l15;
#pragma unroll
        for (int r = 0; r < 4; ++r) {
            int row = r0 + w * 16 + q * 4 + r;
            WfoldT[(long)row * 256 + col] = f2b(acc[c][r]);
        }
    }
}

// ---------------------------------------------------------------------------
// In-place softmax over each contiguous 8192-row of KT ([b*256+d][8192]).
// ---------------------------------------------------------------------------
__global__ __launch_bounds__(64) void softmax_rows(u16* __restrict__ KT) {
    const int row = blockIdx.x;
    const int lane = threadIdx.x;
    u16* p = KT + (long)row * 8192;

    uint4 buf[16];
#pragma unroll
    for (int i = 0; i < 16; ++i) buf[i] = *(const uint4*)(p + (i * 64 + lane) * 8);

    float m = -1e30f;
#pragma unroll
    for (int i = 0; i < 16; ++i) {
        const unsigned* u = (const unsigned*)&buf[i];
#pragma unroll
        for (int j = 0; j < 4; ++j) {
            m = fmaxf(m, fmaxf(b2f((u16)(u[j] & 0xffff)), b2f((u16)(u[j] >> 16))));
        }
    }
#pragma unroll
    for (int s = 32; s > 0; s >>= 1) m = fmaxf(m, __shfl_xor(m, s, 64));

    float sum = 0.f;
#pragma unroll
    for (int i = 0; i < 16; ++i) {
        const unsigned* u = (const unsigned*)&buf[i];
#pragma unroll
        for (int j = 0; j < 4; ++j) {
            sum += exp2f((b2f((u16)(u[j] & 0xffff)) - m) * LOG2E);
            sum += exp2f((b2f((u16)(u[j] >> 16)) - m) * LOG2E);
        }
    }
#pragma unroll
    for (int s = 32; s > 0; s >>= 1) sum += __shfl_xor(sum, s, 64);
    float rl = 1.0f / sum;

#pragma unroll
    for (int i = 0; i < 16; ++i) {
        unsigned* u = (unsigned*)&buf[i];
#pragma unroll
        for (int j = 0; j < 4; ++j) {
            float a = exp2f((b2f((u16)(u[j] & 0xffff)) - m) * LOG2E) * rl;
            float b = exp2f((b2f((u16)(u[j] >> 16)) - m) * LOG2E) * rl;
            u[j] = (unsigned)f2b(a) | ((unsigned)f2b(b) << 16);
        }
        *(uint4*)(p + (i * 64 + lane) * 8) = buf[i];
    }
}

// ---------------------------------------------------------------------------
// BatchNorm over lam^T[(b*256+e)][d]: stats per d over 2048 (b,e) values.
// ---------------------------------------------------------------------------
__global__ __launch_bounds__(256) void bn_kernel(const float* __restrict__ lamT,
                                                 const float* __restrict__ gamma,
                                                 const float* __restrict__ beta,
                                                 u16* __restrict__ bnT) {
    const int d = blockIdx.x;
    const int t = threadIdx.x;
    float vals[8];
    float s = 0.f, ss = 0.f;
#pragma unroll
    for (int i = 0; i < 8; ++i) {
        float v = lamT[(long)(i * 256 + t) * 256 + d];
        vals[i] = v;
        s += v;
        ss += v * v;
    }
#pragma unroll
    for (int sh = 32; sh > 0; sh >>= 1) {
        s += __shfl_xor(s, sh, 64);
        ss += __shfl_xor(ss, sh, 64);
    }
    __shared__ float red[8];
    int w = t >> 6;
    if ((t & 63) == 0) {
        red[w] = s;
        red[w + 4] = ss;
    }
    __syncthreads();
    s = red[0] + red[1] + red[2] + red[3];
    ss = red[4] + red[5] + red[6] + red[7];
    float mean = s * (1.f / 2048.f);
    float var = ss * (1.f / 2048.f) - mean * mean;
    float scale = gamma[d] * rsqrtf(var + 1e-5f);
    float shift = beta[d] - mean * scale;
#pragma unroll
    for (int i = 0; i < 8; ++i)
        bnT[(long)(i * 256 + t) * 256 + d] = f2b(vals[i] * scale + shift);
}

// ---------------------------------------------------------------------------
// outb[b][e] = sum_d bq[d] * bnT[b][e][d]   (folded query bias)
// ---------------------------------------------------------------------------
__global__ __launch_bounds__(256) void outb_kernel(const float* __restrict__ bq,
                                                   const u16* __restrict__ bnT,
                                                   float* __restrict__ outb) {
    int b = blockIdx.x, e = threadIdx.x;
    const u16* rowp = bnT + ((long)b * 256 + e) * 256;
    float s = 0.f;
    for (int dd = 0; dd < 256; ++dd) s += bq[dd] * b2f(rowp[dd]);
    outb[b * 256 + e] = s;
}

// ---------------------------------------------------------------------------
extern "C" void kernel_launch(void* const* d_in, const int* in_sizes, int n_in,
                              void* d_out, int out_size, void* d_ws, size_t ws_size,
                              hipStream_t stream) {
    const float* feat = (const float*)d_in[0];   // (8,8192,256) f32
    const float* W_qk = (const float*)d_in[1];   // (2,256,256) f32
    const float* b_qk = (const float*)d_in[2];   // (2,256) f32
    const float* W_v = (const float*)d_in[3];    // (256,256) f32
    const float* b_v = (const float*)d_in[4];    // (256,) f32
    const float* gamma = (const float*)d_in[5];  // (256,) f32
    const float* beta = (const float*)d_in[6];   // (256,) f32
    float* out = (float*)d_out;                  // (8,8192,256) f32

    char* ws = (char*)d_ws;
    u16* KT = (u16*)(ws);                        // [b][d][n] 33,554,432 B (P after softmax)
    u16* VT = (u16*)(ws + 33554432);             // [b][e][n] 33,554,432 B
    u16* WkT = (u16*)(ws + 67108864);            // 131072 B
    u16* WvT = (u16*)(ws + 67239936);            // 131072 B
    u16* Wqb = (u16*)(ws + 67371008);            // 131072 B
    const size_t base = 67502080;
    float* lamP = (float*)(ws + base);           // S * 2,097,152 B
    size_t avail = (ws_size > base) ? ws_size - base : 0;
    int S = (avail >= 16u * 2097152u) ? 16
          : (avail >= 8u * 2097152u) ? 8
          : (avail >= 4u * 2097152u) ? 4 : 2;
    // post-split-K buffers alias the dead P region (KT):
    float* lamT = (float*)ws;                    // 2,097,152 B
    u16* bnT = (u16*)(ws + 2097152);             // 1,048,576 B
    u16* WfoldT = (u16*)(ws + 3145728);          // 1,048,576 B
    float* outb = (float*)(ws + 4194304);        // 8,192 B

    // 1. weight prep
    prep_w<<<768, 256, 0, stream>>>(W_qk, W_v, WkT, WvT, Wqb);
    // 2. fused full-width K^T / V^T projection
    gemm_kv<<<1024, 256, 0, stream>>>(feat, WkT, WvT, b_qk + 256, b_v, KT, VT);
    // 3. in-place softmax over n -> P^T
    softmax_rows<<<2048, 64, 0, stream>>>(KT);
    // 4. split-K lam partials + reduce
    gemm_splitk<<<dim3(16, 2, S), 256, 0, stream>>>(VT, KT, lamP, 8192 / S);
    reduce_lam<<<512, 256, 0, stream>>>(lamP, lamT, S);
    // 5. BN -> bn^T bf16
    bn_kernel<<<256, 256, 0, stream>>>(lamT, gamma, beta, bnT);
    // 6. folded query bias
    outb_kernel<<<8, 256, 0, stream>>>(b_qk, bnT, outb);
    // 7. Wfold^T = bn^T @ Wq^T
    gemm_fold<<<dim3(32, 4), 256, 0, stream>>>(bnT, Wqb, WfoldT);
    // 8. out = X @ Wfold (+outb), full-width
    gemm_out<<<1024, 256, 0, stream>>>(feat, WfoldT, outb, out);
}